// Round 1
// baseline (1248.527 us; speedup 1.0000x reference)
//
#include <hip/hip_runtime.h>

#define N_NODES 50000
#define N_EDGES 600000
#define D 128
#define NB 16   // nodes per GEMM block

// ---------------------------------------------------------------------------
// GEMM over node rows: out[v][j] (SELF)  = sw(v) * (sum_k X[v][k]*W[j][k] + b[j])
//                      out[v][j] (NEIGH) += (sum_k X[v][k]*W[j][k]) / max(deg[v],1) + b[j]
// Block: 256 threads = 2 groups x 128 output cols; each thread does 8 nodes.
// X tile staged in LDS (8KB); W read from global (64KB, L1/L2 resident).
// ---------------------------------------------------------------------------
template <bool SELF>
__global__ __launch_bounds__(256)
void node_gemm(const float* __restrict__ X, const float* __restrict__ W,
               const float* __restrict__ bias, const float* __restrict__ deg,
               const unsigned char* __restrict__ ntype,
               const float* __restrict__ w_cell, const float* __restrict__ w_gene,
               float* __restrict__ out) {
    __shared__ float xs[NB][D];
    const int node0 = blockIdx.x * NB;
    const int t = threadIdx.x;

    // cooperative load: NB*D = 2048 floats = 512 float4; 256 threads x 2
    {
        const float4* s4 = (const float4*)(X + (size_t)node0 * D);
        float4* d4 = (float4*)&xs[0][0];
        d4[t] = s4[t];
        d4[t + 256] = s4[t + 256];
    }
    __syncthreads();

    const int j = t & 127;   // output column
    const int g = t >> 7;    // node half-group (0/1)

    float acc[8];
#pragma unroll
    for (int n = 0; n < 8; ++n) acc[n] = 0.f;

    const float* Wj = W + j * D;
#pragma unroll
    for (int k = 0; k < D; k += 4) {
        const float4 w = *(const float4*)(Wj + k);
#pragma unroll
        for (int n = 0; n < 8; ++n) {
            const float4 x = *(const float4*)(&xs[g * 8 + n][k]);
            acc[n] = fmaf(w.x, x.x, acc[n]);
            acc[n] = fmaf(w.y, x.y, acc[n]);
            acc[n] = fmaf(w.z, x.z, acc[n]);
            acc[n] = fmaf(w.w, x.w, acc[n]);
        }
    }

    const float b = bias[j];
#pragma unroll
    for (int n = 0; n < 8; ++n) {
        const int v = node0 + g * 8 + n;
        if (SELF) {
            const float sw = ntype[v] ? w_cell[0] : w_gene[0];
            out[(size_t)v * D + j] = sw * (acc[n] + b);
        } else {
            const float rs = 1.f / fmaxf(deg[v], 1.f);
            out[(size_t)v * D + j] += acc[n] * rs + b;
        }
    }
}

// ---------------------------------------------------------------------------
// Edge scatter: fsum[dst] += feat[src]; deg[dst] += 1.  32 threads/edge,
// 4 floats each (float4 load, 4 scalar atomics). 76.8M f32 atomics total.
// ---------------------------------------------------------------------------
__global__ __launch_bounds__(256)
void edge_scatter(const float* __restrict__ feat, const int* __restrict__ src,
                  const int* __restrict__ dst, float* __restrict__ fsum,
                  float* __restrict__ deg) {
    const int i = blockIdx.x * 256 + threadIdx.x;
    const int e = i >> 5;
    const int q = i & 31;
    if (e >= N_EDGES) return;
    const int s = src[e];
    const int t = dst[e];
    const float4 v = *(const float4*)(feat + (size_t)s * D + q * 4);
    float* p = fsum + (size_t)t * D + q * 4;
    atomicAdd(p + 0, v.x);
    atomicAdd(p + 1, v.y);
    atomicAdd(p + 2, v.z);
    atomicAdd(p + 3, v.w);
    if (q == 0) atomicAdd(deg + t, 1.0f);
}

extern "C" void kernel_launch(void* const* d_in, const int* in_sizes, int n_in,
                              void* d_out, int out_size, void* d_ws, size_t ws_size,
                              hipStream_t stream) {
    const float* feat   = (const float*)d_in[0];
    const float* W_self = (const float*)d_in[1];
    const float* b_self = (const float*)d_in[2];
    const float* W_nei  = (const float*)d_in[3];
    const float* b_nei  = (const float*)d_in[4];
    const float* w_cell = (const float*)d_in[5];
    const float* w_gene = (const float*)d_in[6];
    const int*   src    = (const int*)d_in[7];
    const int*   dst    = (const int*)d_in[8];
    const unsigned char* ntype = (const unsigned char*)d_in[9];
    float* out = (float*)d_out;

    float* fsum = (float*)d_ws;                       // [N_NODES*D]
    float* deg  = fsum + (size_t)N_NODES * D;         // [N_NODES]

    // zero accumulators (ws is poisoned 0xAA before every call)
    hipMemsetAsync(d_ws, 0, ((size_t)N_NODES * D + N_NODES) * sizeof(float), stream);

    // self transform: out = sw * (feat @ W_self^T + b_self)
    node_gemm<true><<<N_NODES / NB, 256, 0, stream>>>(
        feat, W_self, b_self, nullptr, ntype, w_cell, w_gene, out);

    // aggregate: fsum[v] = sum_{(u->v)} feat[u], deg[v] = indegree
    edge_scatter<<<(N_EDGES * 32) / 256, 256, 0, stream>>>(feat, src, dst, fsum, deg);

    // neighbor transform: out += (fsum/max(deg,1)) @ W_neigh^T + b_neigh
    node_gemm<false><<<N_NODES / NB, 256, 0, stream>>>(
        fsum, W_nei, b_nei, deg, ntype, w_cell, w_gene, out);
}

// Round 2
// 335.422 us; speedup vs baseline: 3.7223x; 3.7223x over previous
//
#include <hip/hip_runtime.h>

#define N_NODES 50000
#define N_EDGES 600000
#define D 128
#define NB 16        // nodes per GEMM block
#define SCAN_BLK 512
#define SCAN_NBLK ((N_NODES + SCAN_BLK - 1) / SCAN_BLK)   // 98

// ---------------------------------------------------------------------------
// GEMM over node rows.
//  SELF : out[v][j]  = sw(v) * (sum_k X[v][k]*W[j][k] + b[j])
//  NEIGH: out[v][j] += sum_k X[v][k]*W[j][k] + b[j]      (X is already the mean)
// Block: 256 threads = 2 groups x 128 output cols; each thread does 8 nodes.
// ---------------------------------------------------------------------------
template <bool SELF>
__global__ __launch_bounds__(256)
void node_gemm(const float* __restrict__ X, const float* __restrict__ W,
               const float* __restrict__ bias,
               const unsigned char* __restrict__ ntype,
               const float* __restrict__ w_cell, const float* __restrict__ w_gene,
               float* __restrict__ out) {
    __shared__ float xs[NB][D];
    const int node0 = blockIdx.x * NB;
    const int t = threadIdx.x;

    {   // cooperative load: NB*D = 2048 floats = 512 float4
        const float4* s4 = (const float4*)(X + (size_t)node0 * D);
        float4* d4 = (float4*)&xs[0][0];
        d4[t] = s4[t];
        d4[t + 256] = s4[t + 256];
    }
    __syncthreads();

    const int j = t & 127;   // output column
    const int g = t >> 7;    // node half-group (0/1)

    float acc[8];
#pragma unroll
    for (int n = 0; n < 8; ++n) acc[n] = 0.f;

    const float* Wj = W + j * D;
#pragma unroll
    for (int k = 0; k < D; k += 4) {
        const float4 w = *(const float4*)(Wj + k);
#pragma unroll
        for (int n = 0; n < 8; ++n) {
            const float4 x = *(const float4*)(&xs[g * 8 + n][k]);
            acc[n] = fmaf(w.x, x.x, acc[n]);
            acc[n] = fmaf(w.y, x.y, acc[n]);
            acc[n] = fmaf(w.z, x.z, acc[n]);
            acc[n] = fmaf(w.w, x.w, acc[n]);
        }
    }

    const float b = bias[j];
#pragma unroll
    for (int n = 0; n < 8; ++n) {
        const int v = node0 + g * 8 + n;
        if (SELF) {
            const float sw = ntype[v] ? w_cell[0] : w_gene[0];
            out[(size_t)v * D + j] = sw * (acc[n] + b);
        } else {
            out[(size_t)v * D + j] += acc[n] + b;
        }
    }
}

// ---------------------------------------------------------------------------
// CSR build
// ---------------------------------------------------------------------------
__global__ __launch_bounds__(256)
void hist_deg(const int* __restrict__ dst, int* __restrict__ deg) {
    const int e = blockIdx.x * 256 + threadIdx.x;
    if (e < N_EDGES) atomicAdd(&deg[dst[e]], 1);
}

// inclusive block scan of deg -> rowptr[1+i]; per-block totals -> bsum
__global__ __launch_bounds__(SCAN_BLK)
void scanA(const int* __restrict__ deg, int* __restrict__ rowptr,
           int* __restrict__ bsum) {
    __shared__ int tmp[SCAN_BLK];
    const int t = threadIdx.x;
    const int i = blockIdx.x * SCAN_BLK + t;
    tmp[t] = (i < N_NODES) ? deg[i] : 0;
    __syncthreads();
    for (int off = 1; off < SCAN_BLK; off <<= 1) {
        int x = (t >= off) ? tmp[t - off] : 0;
        __syncthreads();
        tmp[t] += x;
        __syncthreads();
    }
    if (i < N_NODES) rowptr[1 + i] = tmp[t];
    if (t == SCAN_BLK - 1) bsum[blockIdx.x] = tmp[t];
}

__global__ void scanB(const int* __restrict__ bsum, int* __restrict__ bofs,
                      int* __restrict__ rowptr) {
    if (threadIdx.x == 0) {
        int run = 0;
        for (int b = 0; b < SCAN_NBLK; ++b) { bofs[b] = run; run += bsum[b]; }
        rowptr[0] = 0;
    }
}

__global__ __launch_bounds__(SCAN_BLK)
void scanC(int* __restrict__ rowptr, const int* __restrict__ bofs) {
    const int i = blockIdx.x * SCAN_BLK + threadIdx.x;
    if (i < N_NODES) rowptr[1 + i] += bofs[blockIdx.x];
}

__global__ __launch_bounds__(256)
void fill_csr(const int* __restrict__ src, const int* __restrict__ dst,
              const int* __restrict__ rowptr, int* __restrict__ cursor,
              int* __restrict__ col) {
    const int e = blockIdx.x * 256 + threadIdx.x;
    if (e >= N_EDGES) return;
    const int d = dst[e];
    const int p = atomicAdd(&cursor[d], 1);
    col[rowptr[d] + p] = src[e];
}

// ---------------------------------------------------------------------------
// Gather-reduce: one wave per node; lane handles 2 columns (float2).
// h[v] = mean_{s in col[rowptr[v]..rowptr[v+1])} feat[s]
// ---------------------------------------------------------------------------
__global__ __launch_bounds__(256)
void gather_mean(const float* __restrict__ feat, const int* __restrict__ rowptr,
                 const int* __restrict__ col, float* __restrict__ h) {
    const int wid = (blockIdx.x * 256 + threadIdx.x) >> 6;   // node id
    const int lane = threadIdx.x & 63;
    if (wid >= N_NODES) return;
    const int beg = rowptr[wid], end = rowptr[wid + 1];
    float ax = 0.f, ay = 0.f;
    for (int i = beg; i < end; ++i) {
        const int s = col[i];
        const float2 v = *(const float2*)(feat + (size_t)s * D + lane * 2);
        ax += v.x; ay += v.y;
    }
    const float rs = 1.f / fmaxf((float)(end - beg), 1.f);
    float2 o; o.x = ax * rs; o.y = ay * rs;
    *(float2*)(h + (size_t)wid * D + lane * 2) = o;
}

extern "C" void kernel_launch(void* const* d_in, const int* in_sizes, int n_in,
                              void* d_out, int out_size, void* d_ws, size_t ws_size,
                              hipStream_t stream) {
    const float* feat   = (const float*)d_in[0];
    const float* W_self = (const float*)d_in[1];
    const float* b_self = (const float*)d_in[2];
    const float* W_nei  = (const float*)d_in[3];
    const float* b_nei  = (const float*)d_in[4];
    const float* w_cell = (const float*)d_in[5];
    const float* w_gene = (const float*)d_in[6];
    const int*   src    = (const int*)d_in[7];
    const int*   dst    = (const int*)d_in[8];
    const unsigned char* ntype = (const unsigned char*)d_in[9];
    float* out = (float*)d_out;

    // workspace layout
    float* h_neigh = (float*)d_ws;                       // [N_NODES*D] f32
    int* rowptr = (int*)(h_neigh + (size_t)N_NODES * D); // [N_NODES+1]
    int* deg    = rowptr + N_NODES + 48;                 // [N_NODES]
    int* cursor = deg + N_NODES;                         // [N_NODES]
    int* bsum   = cursor + N_NODES;                      // [SCAN_NBLK]
    int* bofs   = bsum + 128;                            // [SCAN_NBLK]
    int* col    = bofs + 128;                            // [N_EDGES]

    // zero deg + cursor (contiguous)
    hipMemsetAsync(deg, 0, 2 * N_NODES * sizeof(int), stream);

    // self transform (independent of aggregation)
    node_gemm<true><<<N_NODES / NB, 256, 0, stream>>>(
        feat, W_self, b_self, ntype, w_cell, w_gene, out);

    // CSR build
    hist_deg<<<(N_EDGES + 255) / 256, 256, 0, stream>>>(dst, deg);
    scanA<<<SCAN_NBLK, SCAN_BLK, 0, stream>>>(deg, rowptr, bsum);
    scanB<<<1, 64, 0, stream>>>(bsum, bofs, rowptr);
    scanC<<<SCAN_NBLK, SCAN_BLK, 0, stream>>>(rowptr, bofs);
    fill_csr<<<(N_EDGES + 255) / 256, 256, 0, stream>>>(src, dst, rowptr, cursor, col);

    // mean aggregation (no fp atomics)
    gather_mean<<<(N_NODES * 64 + 255) / 256, 256, 0, stream>>>(feat, rowptr, col, h_neigh);

    // neighbor transform: out += h_neigh @ W_neigh^T + b_neigh
    node_gemm<false><<<N_NODES / NB, 256, 0, stream>>>(
        h_neigh, W_nei, b_nei, ntype, w_cell, w_gene, out);
}

// Round 3
// 233.040 us; speedup vs baseline: 5.3576x; 1.4393x over previous
//
#include <hip/hip_runtime.h>

#define N_NODES 50000
#define N_EDGES 600000
#define D 128
#define SCAN_BLK 512
#define SCAN_NBLK ((N_NODES + SCAN_BLK - 1) / SCAN_BLK)   // 98
#define GNB 64   // nodes per fused-GEMM block (4 waves x 16 rows)

typedef __attribute__((ext_vector_type(8))) short bf16x8;
typedef __attribute__((ext_vector_type(4))) float f32x4;

static __device__ __forceinline__ unsigned short f2bf(float f) {
    unsigned u = __float_as_uint(f);
    unsigned r = (u + 0x7FFFu + ((u >> 16) & 1u)) >> 16;   // RNE
    return (unsigned short)r;
}
static __device__ __forceinline__ float bf2f(unsigned short b) {
    return __uint_as_float(((unsigned)b) << 16);
}

// ---------------------------------------------------------------------------
// f32 -> bf16 converts
// ---------------------------------------------------------------------------
__global__ __launch_bounds__(256)
void convF(const float* __restrict__ in, unsigned short* __restrict__ out) {
    const int i = blockIdx.x * 256 + threadIdx.x;       // 1.6M threads, 4 elems each
    const float4 v = ((const float4*)in)[i];
    ushort4 o;
    o.x = f2bf(v.x); o.y = f2bf(v.y); o.z = f2bf(v.z); o.w = f2bf(v.w);
    ((ushort4*)out)[i] = o;
}

__global__ __launch_bounds__(256)
void convW(const float* __restrict__ Ws, const float* __restrict__ Wn,
           unsigned short* __restrict__ Wsb, unsigned short* __restrict__ Wnb) {
    const int i = blockIdx.x * 256 + threadIdx.x;       // 32768 threads
    if (i < D * D) Wsb[i] = f2bf(Ws[i]);
    else           Wnb[i - D * D] = f2bf(Wn[i - D * D]);
}

// ---------------------------------------------------------------------------
// CSR build
// ---------------------------------------------------------------------------
__global__ __launch_bounds__(256)
void hist_deg(const int* __restrict__ dst, int* __restrict__ deg) {
    const int e = blockIdx.x * 256 + threadIdx.x;
    if (e < N_EDGES) atomicAdd(&deg[dst[e]], 1);
}

__global__ __launch_bounds__(SCAN_BLK)
void scanA(const int* __restrict__ deg, int* __restrict__ rowptr,
           int* __restrict__ bsum) {
    __shared__ int tmp[SCAN_BLK];
    const int t = threadIdx.x;
    const int i = blockIdx.x * SCAN_BLK + t;
    tmp[t] = (i < N_NODES) ? deg[i] : 0;
    __syncthreads();
    for (int off = 1; off < SCAN_BLK; off <<= 1) {
        int x = (t >= off) ? tmp[t - off] : 0;
        __syncthreads();
        tmp[t] += x;
        __syncthreads();
    }
    if (i < N_NODES) rowptr[1 + i] = tmp[t];
    if (t == SCAN_BLK - 1) bsum[blockIdx.x] = tmp[t];
}

__global__ void scanB(const int* __restrict__ bsum, int* __restrict__ bofs,
                      int* __restrict__ rowptr) {
    if (threadIdx.x == 0) {
        int run = 0;
        for (int b = 0; b < SCAN_NBLK; ++b) { bofs[b] = run; run += bsum[b]; }
        rowptr[0] = 0;
    }
}

__global__ __launch_bounds__(SCAN_BLK)
void scanC(int* __restrict__ rowptr, const int* __restrict__ bofs) {
    const int i = blockIdx.x * SCAN_BLK + threadIdx.x;
    if (i < N_NODES) rowptr[1 + i] += bofs[blockIdx.x];
}

__global__ __launch_bounds__(256)
void fill_csr(const int* __restrict__ src, const int* __restrict__ dst,
              const int* __restrict__ rowptr, int* __restrict__ cursor,
              int* __restrict__ col) {
    const int e = blockIdx.x * 256 + threadIdx.x;
    if (e >= N_EDGES) return;
    const int d = dst[e];
    const int p = atomicAdd(&cursor[d], 1);
    col[rowptr[d] + p] = src[e];
}

// ---------------------------------------------------------------------------
// Gather-reduce (bf16 in, bf16 out, f32 accumulate). One wave per node,
// lane = 2 cols; 4-wide edge unroll for memory-level parallelism.
// ---------------------------------------------------------------------------
__global__ __launch_bounds__(256)
void gather_mean(const unsigned short* __restrict__ fb,
                 const int* __restrict__ rowptr, const int* __restrict__ col,
                 unsigned short* __restrict__ hb) {
    const int wid = (blockIdx.x * 256 + threadIdx.x) >> 6;
    const int lane = threadIdx.x & 63;
    if (wid >= N_NODES) return;
    const int beg = rowptr[wid], end = rowptr[wid + 1];
    float ax = 0.f, ay = 0.f;
    int i = beg;
    for (; i + 3 < end; i += 4) {
        const int s0 = col[i], s1 = col[i + 1], s2 = col[i + 2], s3 = col[i + 3];
        const unsigned u0 = *(const unsigned*)(fb + (size_t)s0 * D + lane * 2);
        const unsigned u1 = *(const unsigned*)(fb + (size_t)s1 * D + lane * 2);
        const unsigned u2 = *(const unsigned*)(fb + (size_t)s2 * D + lane * 2);
        const unsigned u3 = *(const unsigned*)(fb + (size_t)s3 * D + lane * 2);
        ax += bf2f((unsigned short)u0) + bf2f((unsigned short)u1)
            + bf2f((unsigned short)u2) + bf2f((unsigned short)u3);
        ay += bf2f((unsigned short)(u0 >> 16)) + bf2f((unsigned short)(u1 >> 16))
            + bf2f((unsigned short)(u2 >> 16)) + bf2f((unsigned short)(u3 >> 16));
    }
    for (; i < end; ++i) {
        const unsigned u = *(const unsigned*)(fb + (size_t)col[i] * D + lane * 2);
        ax += bf2f((unsigned short)u);
        ay += bf2f((unsigned short)(u >> 16));
    }
    const float rs = 1.f / fmaxf((float)(end - beg), 1.f);
    const unsigned o = (unsigned)f2bf(ax * rs) | ((unsigned)f2bf(ay * rs) << 16);
    *(unsigned*)(hb + (size_t)wid * D + lane * 2) = o;
}

// ---------------------------------------------------------------------------
// Fused MFMA GEMM: out[v][j] = sw(v)*(fb[v]·Wsb[j] + bs[j]) + hb[v]·Wnb[j] + bn[j]
// Block = 4 waves; wave handles 16 rows x 128 cols (8 j-tiles), K-loop 4x32.
// A frag: lane l -> row (l&15), k = ks*32 + (l>>4)*8 .. +8 (contiguous bf16x8).
// B frag: lane l -> W row (j0 + (l&15)), same k run.
// C/D   : reg r of lane l -> row (l>>4)*4 + r, col (l&15)   [guide §3, m89]
// ---------------------------------------------------------------------------
__global__ __launch_bounds__(256)
void fused_gemm(const unsigned short* __restrict__ fb,
                const unsigned short* __restrict__ hb,
                const unsigned short* __restrict__ Wsb,
                const unsigned short* __restrict__ Wnb,
                const float* __restrict__ bs, const float* __restrict__ bn,
                const unsigned char* __restrict__ ntype,
                const float* __restrict__ w_cell, const float* __restrict__ w_gene,
                float* __restrict__ out) {
    const int t = threadIdx.x;
    const int w = t >> 6, l = t & 63;
    const int lr = l & 15;
    const int kb = (l >> 4) * 8;
    const int arow = blockIdx.x * GNB + w * 16 + lr;
    const size_t arowc = (size_t)min(arow, N_NODES - 1);

    f32x4 accS[8], accN[8];
#pragma unroll
    for (int j = 0; j < 8; ++j) {
        accS[j] = (f32x4){0.f, 0.f, 0.f, 0.f};
        accN[j] = (f32x4){0.f, 0.f, 0.f, 0.f};
    }

#pragma unroll
    for (int ks = 0; ks < 4; ++ks) {
        const int ko = ks * 32 + kb;
        const bf16x8 aS = *(const bf16x8*)(fb + arowc * D + ko);
        const bf16x8 aN = *(const bf16x8*)(hb + arowc * D + ko);
#pragma unroll
        for (int j = 0; j < 8; ++j) {
            const bf16x8 bS = *(const bf16x8*)(Wsb + (size_t)(j * 16 + lr) * D + ko);
            const bf16x8 bN = *(const bf16x8*)(Wnb + (size_t)(j * 16 + lr) * D + ko);
            accS[j] = __builtin_amdgcn_mfma_f32_16x16x32_bf16(aS, bS, accS[j], 0, 0, 0);
            accN[j] = __builtin_amdgcn_mfma_f32_16x16x32_bf16(aN, bN, accN[j], 0, 0, 0);
        }
    }

    const int drow0 = blockIdx.x * GNB + w * 16 + (l >> 4) * 4;
#pragma unroll
    for (int r = 0; r < 4; ++r) {
        const int v = drow0 + r;
        if (v < N_NODES) {
            const float sw = ntype[v] ? w_cell[0] : w_gene[0];
#pragma unroll
            for (int j = 0; j < 8; ++j) {
                const int c = j * 16 + lr;
                out[(size_t)v * D + c] = sw * (accS[j][r] + bs[c]) + accN[j][r] + bn[c];
            }
        }
    }
}

extern "C" void kernel_launch(void* const* d_in, const int* in_sizes, int n_in,
                              void* d_out, int out_size, void* d_ws, size_t ws_size,
                              hipStream_t stream) {
    const float* feat   = (const float*)d_in[0];
    const float* W_self = (const float*)d_in[1];
    const float* b_self = (const float*)d_in[2];
    const float* W_nei  = (const float*)d_in[3];
    const float* b_nei  = (const float*)d_in[4];
    const float* w_cell = (const float*)d_in[5];
    const float* w_gene = (const float*)d_in[6];
    const int*   src    = (const int*)d_in[7];
    const int*   dst    = (const int*)d_in[8];
    const unsigned char* ntype = (const unsigned char*)d_in[9];
    float* out = (float*)d_out;

    // workspace layout (bytes): fb 12.8M | hb 12.8M | Wsb/Wnb 64K | ints ~3.2M
    unsigned short* fb  = (unsigned short*)d_ws;
    unsigned short* hb  = fb + (size_t)N_NODES * D;
    unsigned short* Wsb = hb + (size_t)N_NODES * D;
    unsigned short* Wnb = Wsb + D * D;
    int* rowptr = (int*)(Wnb + D * D);                   // [N_NODES+1]
    int* deg    = rowptr + N_NODES + 4;                  // [N_NODES]
    int* cursor = deg + N_NODES;                         // [N_NODES]
    int* bsum   = cursor + N_NODES;                      // [SCAN_NBLK]
    int* bofs   = bsum + 128;                            // [SCAN_NBLK]
    int* col    = bofs + 128;                            // [N_EDGES]

    hipMemsetAsync(deg, 0, 2 * N_NODES * sizeof(int), stream);

    // bf16 casts
    convF<<<(N_NODES * D / 4) / 256, 256, 0, stream>>>(feat, fb);
    convW<<<(2 * D * D) / 256, 256, 0, stream>>>(W_self, W_nei, Wsb, Wnb);

    // CSR build
    hist_deg<<<(N_EDGES + 255) / 256, 256, 0, stream>>>(dst, deg);
    scanA<<<SCAN_NBLK, SCAN_BLK, 0, stream>>>(deg, rowptr, bsum);
    scanB<<<1, 64, 0, stream>>>(bsum, bofs, rowptr);
    scanC<<<SCAN_NBLK, SCAN_BLK, 0, stream>>>(rowptr, bofs);
    fill_csr<<<(N_EDGES + 255) / 256, 256, 0, stream>>>(src, dst, rowptr, cursor, col);

    // mean aggregation
    gather_mean<<<(N_NODES * 64 + 255) / 256, 256, 0, stream>>>(fb, rowptr, col, hb);

    // fused self+neigh transform
    fused_gemm<<<(N_NODES + GNB - 1) / GNB, 256, 0, stream>>>(
        fb, hb, Wsb, Wnb, b_self, b_nei, ntype, w_cell, w_gene, out);
}